// Round 1
// baseline (186.995 us; speedup 1.0000x reference)
//
#include <hip/hip_runtime.h>
#include <math.h>

// ---------------------------------------------------------------- fusion attn
__global__ __launch_bounds__(256) void k_fuse1(
    const float* __restrict__ x1, const float* __restrict__ x2,
    const float* __restrict__ qw, const float* __restrict__ qb,
    const float* __restrict__ kw, const float* __restrict__ kb,
    const float* __restrict__ vw, const float* __restrict__ vb,
    float* __restrict__ s, float* __restrict__ v, int n) {
  int nd = blockIdx.x * blockDim.x + threadIdx.x;
  if (nd >= n) return;
  float a[10], b[10];
#pragma unroll
  for (int c = 0; c < 10; ++c) { a[c] = x1[nd * 10 + c]; b[c] = x2[nd * 10 + c]; }
  float dot = 0.f;
#pragma unroll
  for (int h = 0; h < 16; ++h) {
    float q = qb[h], k = kb[h];
#pragma unroll
    for (int c = 0; c < 10; ++c) { q += a[c] * qw[c * 16 + h]; k += b[c] * kw[c * 16 + h]; }
    dot += q * k;
  }
  s[nd] = dot;
#pragma unroll
  for (int j = 0; j < 16; ++j) {
    float acc = vb[j];
#pragma unroll
    for (int c = 0; c < 10; ++c) acc += a[c] * vw[c * 16 + j] + b[c] * vw[(10 + c) * 16 + j];
    v[nd * 16 + j] = acc;
  }
}

__global__ __launch_bounds__(1024) void k_softmax_reduce(
    const float* __restrict__ s, float* __restrict__ red, int n) {
  __shared__ float lds[1024];
  int t = threadIdx.x;
  float m = -1e30f;
  for (int i = t; i < n; i += 1024) m = fmaxf(m, s[i]);
  lds[t] = m; __syncthreads();
  for (int o = 512; o; o >>= 1) { if (t < o) lds[t] = fmaxf(lds[t], lds[t + o]); __syncthreads(); }
  float gm = lds[0]; __syncthreads();
  float sm = 0.f;
  for (int i = t; i < n; i += 1024) sm += expf(s[i] - gm);
  lds[t] = sm; __syncthreads();
  for (int o = 512; o; o >>= 1) { if (t < o) lds[t] += lds[t + o]; __syncthreads(); }
  if (t == 0) { red[0] = gm; red[1] = lds[0]; }
}

__global__ __launch_bounds__(256) void k_fuse2(
    const float* __restrict__ s, const float* __restrict__ v,
    const float* __restrict__ red, float* __restrict__ fused, int n) {
  int nd = blockIdx.x * blockDim.x + threadIdx.x;
  if (nd >= n) return;
  float a = expf(s[nd] - red[0]) / red[1];
#pragma unroll
  for (int j = 0; j < 16; ++j) fused[nd * 16 + j] = a * v[nd * 16 + j];
}

// ---------------------------------------------------------------- CSR (by dst)
__global__ __launch_bounds__(256) void k_indeg(
    const int* __restrict__ ei1, int* __restrict__ indeg, int E, int n) {
  int t = blockIdx.x * blockDim.x + threadIdx.x;
  if (t >= E + n) return;
  int dst = (t < E) ? ei1[t] : (t - E);
  atomicAdd(&indeg[dst], 1);
}

__global__ __launch_bounds__(1024) void k_scan(
    const int* __restrict__ indeg, int* __restrict__ offs, int n) {
  __shared__ int lds[1024];
  int t = threadIdx.x;
  int loc[8]; int sum = 0;
#pragma unroll
  for (int k = 0; k < 8; ++k) {
    int i = t * 8 + k;
    loc[k] = (i < n) ? indeg[i] : 0;
    sum += loc[k];
  }
  lds[t] = sum; __syncthreads();
  for (int o = 1; o < 1024; o <<= 1) {
    int add = (t >= o) ? lds[t - o] : 0;
    __syncthreads();
    lds[t] += add;
    __syncthreads();
  }
  int run = lds[t] - sum;  // exclusive base
#pragma unroll
  for (int k = 0; k < 8; ++k) {
    int i = t * 8 + k;
    if (i < n) offs[i] = run;
    run += loc[k];
  }
  if (t == 0) offs[n] = lds[1023];
}

__global__ __launch_bounds__(256) void k_scatter(
    const int* __restrict__ ei0, const int* __restrict__ ei1,
    const int* __restrict__ offs, int* __restrict__ cursor,
    int* __restrict__ csr_src, int E, int n) {
  int t = blockIdx.x * blockDim.x + threadIdx.x;
  if (t >= E + n) return;
  int src, dst;
  if (t < E) { src = ei0[t]; dst = ei1[t]; } else { src = dst = t - E; }
  int pos = atomicAdd(&cursor[dst], 1);
  csr_src[offs[dst] + pos] = src;
}

// ---------------------------------------------------------------- A bitmask
__global__ __launch_bounds__(256) void k_bits(
    const int* __restrict__ ei0, const int* __restrict__ ei1,
    unsigned int* __restrict__ bits, int E, int n, int wpr) {
  int t = blockIdx.x * blockDim.x + threadIdx.x;
  if (t >= E + n) return;
  int i, j;
  if (t < E) { i = ei0[t]; j = ei1[t]; } else { i = j = t - E; }
  atomicOr(&bits[(size_t)i * wpr + (j >> 5)], 1u << (j & 31));
}

// ---------------------------------------------------------------- GAT node-side
template <int FIN, int FOUT, int H, int C>
__global__ __launch_bounds__(256) void k_gat_node(
    const float* __restrict__ x, const float* __restrict__ W,
    const float* __restrict__ a_s, const float* __restrict__ a_d,
    float* __restrict__ h, float* __restrict__ as_, float* __restrict__ ad_, int n) {
  __shared__ float sW[FIN * FOUT];
  __shared__ float sas[H * C], sad[H * C];
  for (int i = threadIdx.x; i < FIN * FOUT; i += blockDim.x) sW[i] = W[i];
  if (threadIdx.x < H * C) { sas[threadIdx.x] = a_s[threadIdx.x]; sad[threadIdx.x] = a_d[threadIdx.x]; }
  __syncthreads();
  int nd = blockIdx.x * blockDim.x + threadIdx.x;
  if (nd >= n) return;
  float xr[FIN];
#pragma unroll
  for (int c = 0; c < FIN; ++c) xr[c] = x[nd * FIN + c];
  float hv[FOUT];
#pragma unroll
  for (int f = 0; f < FOUT; ++f) {
    float acc = 0.f;
#pragma unroll
    for (int c = 0; c < FIN; ++c) acc += xr[c] * sW[c * FOUT + f];
    hv[f] = acc;
    h[nd * FOUT + f] = acc;
  }
#pragma unroll
  for (int hh = 0; hh < H; ++hh) {
    float a1 = 0.f, a2 = 0.f;
#pragma unroll
    for (int c = 0; c < C; ++c) { a1 += hv[hh * C + c] * sas[hh * C + c]; a2 += hv[hh * C + c] * sad[hh * C + c]; }
    as_[nd * H + hh] = a1;
    ad_[nd * H + hh] = a2;
  }
}

// ---------------------------------------------------------------- GAT aggregate
// one wave (64 lanes) per dst node; 2-pass (max; exp/acc) over in-edges
template <int FOUT, int H, int C>
__global__ __launch_bounds__(256) void k_gat_agg(
    const float* __restrict__ h, const float* __restrict__ as_,
    const float* __restrict__ ad_, const float* __restrict__ b,
    const int* __restrict__ offs, const int* __restrict__ csr_src,
    float* __restrict__ out, int n) {
  int wave = threadIdx.x >> 6;
  int lane = threadIdx.x & 63;
  int nd = blockIdx.x * (blockDim.x >> 6) + wave;
  if (nd >= n) return;
  int beg = offs[nd], end = offs[nd + 1];
  float adv[H];
#pragma unroll
  for (int hh = 0; hh < H; ++hh) adv[hh] = ad_[nd * H + hh];
  // pass A: per-head max
  float m[H];
#pragma unroll
  for (int hh = 0; hh < H; ++hh) m[hh] = -1e30f;
  for (int idx = beg + lane; idx < end; idx += 64) {
    int s = csr_src[idx];
#pragma unroll
    for (int hh = 0; hh < H; ++hh) {
      float e = as_[s * H + hh] + adv[hh];
      e = (e >= 0.f) ? e : 0.2f * e;
      m[hh] = fmaxf(m[hh], e);
    }
  }
#pragma unroll
  for (int hh = 0; hh < H; ++hh)
    for (int o = 32; o; o >>= 1) m[hh] = fmaxf(m[hh], __shfl_xor(m[hh], o, 64));
  // pass B: denom + weighted sum
  float den[H];
  float num[FOUT];
#pragma unroll
  for (int hh = 0; hh < H; ++hh) den[hh] = 0.f;
#pragma unroll
  for (int f = 0; f < FOUT; ++f) num[f] = 0.f;
  for (int idx = beg + lane; idx < end; idx += 64) {
    int s = csr_src[idx];
#pragma unroll
    for (int hh = 0; hh < H; ++hh) {
      float e = as_[s * H + hh] + adv[hh];
      e = (e >= 0.f) ? e : 0.2f * e;
      float ex = expf(e - m[hh]);
      den[hh] += ex;
#pragma unroll
      for (int c = 0; c < C; ++c) num[hh * C + c] += ex * h[s * FOUT + hh * C + c];
    }
  }
#pragma unroll
  for (int hh = 0; hh < H; ++hh)
    for (int o = 32; o; o >>= 1) den[hh] += __shfl_xor(den[hh], o, 64);
#pragma unroll
  for (int f = 0; f < FOUT; ++f)
    for (int o = 32; o; o >>= 1) num[f] += __shfl_xor(num[f], o, 64);
  if (lane == 0) {
#pragma unroll
    for (int f = 0; f < FOUT; ++f)
      out[nd * FOUT + f] = num[f] / (den[f / C] + 1e-16f) + b[f];
  }
}

// ---------------------------------------------------------------- final: R3 + scores
__global__ __launch_bounds__(256) void k_final(
    const float* __restrict__ x4, const unsigned int* __restrict__ bits,
    const float* __restrict__ w2, float* __restrict__ out, int n, int wpr) {
  int wave = threadIdx.x >> 6;
  int lane = threadIdx.x & 63;
  int row = blockIdx.x * (blockDim.x >> 6) + wave;
  if (row >= n) return;
  float sum[8];
#pragma unroll
  for (int c = 0; c < 8; ++c) sum[c] = 0.f;
  int cnt = 0;
  for (int w = lane; w < wpr; w += 64) {
    unsigned int word = bits[(size_t)row * wpr + w];
    cnt += __popc(word);
    while (word) {
      int bpos = __ffs(word) - 1;
      word &= word - 1;
      int j = w * 32 + bpos;
#pragma unroll
      for (int c = 0; c < 8; ++c) sum[c] += x4[j * 8 + c];
    }
  }
  for (int o = 32; o; o >>= 1) {
    cnt += __shfl_xor(cnt, o, 64);
#pragma unroll
    for (int c = 0; c < 8; ++c) sum[c] += __shfl_xor(sum[c], o, 64);
  }
  if (lane == 0) {
    float inv = 1.f / (float)cnt;  // cnt >= 1 (diagonal always set)
    float local = 0.f, glob = 0.f;
#pragma unroll
    for (int c = 0; c < 8; ++c) {
      float r = sum[c] * inv;
      local += x4[row * 8 + c] * r;
      glob += r * w2[c];
    }
    out[row] = local + glob;
  }
}

// ---------------------------------------------------------------- launch
extern "C" void kernel_launch(void* const* d_in, const int* in_sizes, int n_in,
                              void* d_out, int out_size, void* d_ws, size_t ws_size,
                              hipStream_t stream) {
  const float* x1 = (const float*)d_in[0];
  const float* x2 = (const float*)d_in[1];
  const int* ei = (const int*)d_in[2];
  const float* qw = (const float*)d_in[4];
  const float* qb = (const float*)d_in[5];
  const float* kw = (const float*)d_in[6];
  const float* kb = (const float*)d_in[7];
  const float* vw = (const float*)d_in[8];
  const float* vb = (const float*)d_in[9];
  const float* W1 = (const float*)d_in[10];
  const float* a1s = (const float*)d_in[11];
  const float* a1d = (const float*)d_in[12];
  const float* b1 = (const float*)d_in[13];
  const float* W2 = (const float*)d_in[14];
  const float* a2s = (const float*)d_in[15];
  const float* a2d = (const float*)d_in[16];
  const float* b2 = (const float*)d_in[17];
  const float* W3 = (const float*)d_in[18];
  const float* a3s = (const float*)d_in[19];
  const float* a3d = (const float*)d_in[20];
  const float* b3 = (const float*)d_in[21];
  const float* w2 = (const float*)d_in[22];

  const int N = in_sizes[0] / 10;
  const int E = in_sizes[2] / 2;
  const int* ei0 = ei;
  const int* ei1 = ei + E;
  const int wpr = (N + 31) / 32;  // bitmask words per row

  // workspace carve-up (256B aligned)
  char* w = (char*)d_ws;
  auto alloc = [&](size_t bytes) {
    void* p = (void*)w;
    w += (bytes + 255) & ~(size_t)255;
    return p;
  };
  float* s_buf  = (float*)alloc((size_t)N * 4);
  float* v_buf  = (float*)alloc((size_t)N * 16 * 4);
  float* fused  = (float*)alloc((size_t)N * 16 * 4);
  float* red    = (float*)alloc(256);
  float* hbuf   = (float*)alloc((size_t)N * 32 * 4);
  float* asb    = (float*)alloc((size_t)N * 8 * 4);
  float* adb    = (float*)alloc((size_t)N * 8 * 4);
  float* o1     = (float*)alloc((size_t)N * 32 * 4);
  float* o2     = (float*)alloc((size_t)N * 16 * 4);
  float* x4     = (float*)alloc((size_t)N * 8 * 4);
  int* indeg    = (int*)alloc((size_t)N * 4);
  int* cursor   = (int*)alloc((size_t)N * 4);
  int* offs     = (int*)alloc((size_t)(N + 1) * 4);
  int* csr_src  = (int*)alloc((size_t)(E + N) * 4);
  unsigned int* bits = (unsigned int*)alloc((size_t)N * wpr * 4);

  hipMemsetAsync(indeg, 0, (size_t)N * 4, stream);
  hipMemsetAsync(cursor, 0, (size_t)N * 4, stream);
  hipMemsetAsync(bits, 0, (size_t)N * wpr * 4, stream);

  const int TB = 256;
  int nb_nodes = (N + TB - 1) / TB;
  int nb_edges = (E + N + TB - 1) / TB;
  int nb_waves = (N + 3) / 4;  // 4 waves per 256-thread block

  k_fuse1<<<nb_nodes, TB, 0, stream>>>(x1, x2, qw, qb, kw, kb, vw, vb, s_buf, v_buf, N);
  k_softmax_reduce<<<1, 1024, 0, stream>>>(s_buf, red, N);
  k_fuse2<<<nb_nodes, TB, 0, stream>>>(s_buf, v_buf, red, fused, N);

  k_indeg<<<nb_edges, TB, 0, stream>>>(ei1, indeg, E, N);
  k_scan<<<1, 1024, 0, stream>>>(indeg, offs, N);
  k_scatter<<<nb_edges, TB, 0, stream>>>(ei0, ei1, offs, cursor, csr_src, E, N);
  k_bits<<<nb_edges, TB, 0, stream>>>(ei0, ei1, bits, E, N, wpr);

  // GAT layer 1: 16 -> 32, H=8, C=4
  k_gat_node<16, 32, 8, 4><<<nb_nodes, TB, 0, stream>>>(fused, W1, a1s, a1d, hbuf, asb, adb, N);
  k_gat_agg<32, 8, 4><<<nb_waves, TB, 0, stream>>>(hbuf, asb, adb, b1, offs, csr_src, o1, N);
  // GAT layer 2: 32 -> 16, H=4, C=4
  k_gat_node<32, 16, 4, 4><<<nb_nodes, TB, 0, stream>>>(o1, W2, a2s, a2d, hbuf, asb, adb, N);
  k_gat_agg<16, 4, 4><<<nb_waves, TB, 0, stream>>>(hbuf, asb, adb, b2, offs, csr_src, o2, N);
  // GAT layer 3: 16 -> 8, H=2, C=4
  k_gat_node<16, 8, 2, 4><<<nb_nodes, TB, 0, stream>>>(o2, W3, a3s, a3d, hbuf, asb, adb, N);
  k_gat_agg<8, 2, 4><<<nb_waves, TB, 0, stream>>>(hbuf, asb, adb, b3, offs, csr_src, x4, N);

  k_final<<<nb_waves, TB, 0, stream>>>(x4, bits, w2, (float*)d_out, N, wpr);
}

// Round 2
// 146.295 us; speedup vs baseline: 1.2782x; 1.2782x over previous
//
#include <hip/hip_runtime.h>
#include <math.h>

// ---------------------------------------------------------------- helpers
__device__ __forceinline__ float wred_sum(float x) {
#pragma unroll
  for (int o = 32; o; o >>= 1) x += __shfl_xor(x, o, 64);
  return x;
}

template <int K>
__device__ __forceinline__ void loadf(const float* __restrict__ p, float (&r)[K]) {
  if constexpr (K % 4 == 0) {
    const float4* p4 = (const float4*)p;
#pragma unroll
    for (int i = 0; i < K / 4; ++i) {
      float4 t = p4[i];
      r[4 * i + 0] = t.x; r[4 * i + 1] = t.y; r[4 * i + 2] = t.z; r[4 * i + 3] = t.w;
    }
  } else if constexpr (K == 2) {
    float2 t = *(const float2*)p;
    r[0] = t.x; r[1] = t.y;
  }
}

// ------------------------------------------- fuse1 + indeg + bitmask (E+N threads)
__global__ __launch_bounds__(256) void k_fuse1_prep(
    const float* __restrict__ x1, const float* __restrict__ x2,
    const float* __restrict__ qw, const float* __restrict__ qb,
    const float* __restrict__ kw, const float* __restrict__ kb,
    const float* __restrict__ vw, const float* __restrict__ vb,
    float* __restrict__ s, float* __restrict__ v,
    const int* __restrict__ ei0, const int* __restrict__ ei1,
    int* __restrict__ indeg, unsigned int* __restrict__ bits,
    int E, int n, int wpr) {
  int t = blockIdx.x * blockDim.x + threadIdx.x;
  if (t < n) {
    float a[10], b[10];
#pragma unroll
    for (int c = 0; c < 10; ++c) { a[c] = x1[t * 10 + c]; b[c] = x2[t * 10 + c]; }
    float dot = 0.f;
#pragma unroll
    for (int h = 0; h < 16; ++h) {
      float q = qb[h], k = kb[h];
#pragma unroll
      for (int c = 0; c < 10; ++c) { q += a[c] * qw[c * 16 + h]; k += b[c] * kw[c * 16 + h]; }
      dot += q * k;
    }
    s[t] = dot;
#pragma unroll
    for (int j = 0; j < 16; ++j) {
      float acc = vb[j];
#pragma unroll
      for (int c = 0; c < 10; ++c) acc += a[c] * vw[c * 16 + j] + b[c] * vw[(10 + c) * 16 + j];
      v[t * 16 + j] = acc;
    }
  }
  if (t < E + n) {
    int src, dst;
    if (t < E) { src = ei0[t]; dst = ei1[t]; } else { src = dst = t - E; }
    atomicAdd(&indeg[dst], 1);
    atomicOr(&bits[(size_t)src * wpr + (dst >> 5)], 1u << (dst & 31));
  }
}

// ---------------------------------------------------------------- scan (1 block)
__global__ __launch_bounds__(1024) void k_scan(
    const int* __restrict__ indeg, int* __restrict__ offs, int n) {
  __shared__ int lds[1024];
  int t = threadIdx.x;
  int loc[8]; int sum = 0;
#pragma unroll
  for (int k = 0; k < 8; ++k) {
    int i = t * 8 + k;
    loc[k] = (i < n) ? indeg[i] : 0;
    sum += loc[k];
  }
  lds[t] = sum; __syncthreads();
  for (int o = 1; o < 1024; o <<= 1) {
    int add = (t >= o) ? lds[t - o] : 0;
    __syncthreads();
    lds[t] += add;
    __syncthreads();
  }
  int run = lds[t] - sum;
#pragma unroll
  for (int k = 0; k < 8; ++k) {
    int i = t * 8 + k;
    if (i < n) offs[i] = run;
    run += loc[k];
  }
  if (t == 0) offs[n] = lds[1023];
}

__global__ __launch_bounds__(256) void k_scatter(
    const int* __restrict__ ei0, const int* __restrict__ ei1,
    const int* __restrict__ offs, int* __restrict__ cursor,
    int* __restrict__ csr_src, int E, int n) {
  int t = blockIdx.x * blockDim.x + threadIdx.x;
  if (t >= E + n) return;
  int src, dst;
  if (t < E) { src = ei0[t]; dst = ei1[t]; } else { src = dst = t - E; }
  int pos = atomicAdd(&cursor[dst], 1);
  csr_src[offs[dst] + pos] = src;
}

// -------------------------- fuse2 (block-redundant softmax) + GAT1 node transform
__global__ __launch_bounds__(256) void k_fuse2n1(
    const float* __restrict__ s, const float* __restrict__ v,
    const float* __restrict__ W1, const float* __restrict__ a1s,
    const float* __restrict__ a1d,
    float* __restrict__ h1, float* __restrict__ as1, float* __restrict__ ad1, int n) {
  __shared__ float sW[16 * 32];
  __shared__ float sas[32], sad[32];
  __shared__ float red[256];
  int t = threadIdx.x;
  for (int i = t; i < 512; i += 256) sW[i] = W1[i];
  if (t < 32) { sas[t] = a1s[t]; sad[t] = a1d[t]; }
  // global softmax stats (each block redundantly; s is 32 KB, L2-resident)
  float m = -1e30f;
  for (int i = t; i < n; i += 256) m = fmaxf(m, s[i]);
  red[t] = m; __syncthreads();
  for (int o = 128; o; o >>= 1) { if (t < o) red[t] = fmaxf(red[t], red[t + o]); __syncthreads(); }
  float gm = red[0]; __syncthreads();
  float sm = 0.f;
  for (int i = t; i < n; i += 256) sm += __expf(s[i] - gm);
  red[t] = sm; __syncthreads();
  for (int o = 128; o; o >>= 1) { if (t < o) red[t] += red[t + o]; __syncthreads(); }
  float tot = red[0];

  int nd = blockIdx.x * 256 + t;
  if (nd >= n) return;
  float a = __expf(s[nd] - gm) / tot;
  float f[16]; loadf<16>(v + nd * 16, f);
#pragma unroll
  for (int j = 0; j < 16; ++j) f[j] *= a;
  float hv[32];
#pragma unroll
  for (int o2 = 0; o2 < 32; ++o2) {
    float acc = 0.f;
#pragma unroll
    for (int c = 0; c < 16; ++c) acc += f[c] * sW[c * 32 + o2];
    hv[o2] = acc;
    h1[nd * 32 + o2] = acc;
  }
#pragma unroll
  for (int hh = 0; hh < 8; ++hh) {
    float a1 = 0.f, a2 = 0.f;
#pragma unroll
    for (int c = 0; c < 4; ++c) {
      a1 += hv[hh * 4 + c] * sas[hh * 4 + c];
      a2 += hv[hh * 4 + c] * sad[hh * 4 + c];
    }
    as1[nd * 8 + hh] = a1;
    ad1[nd * 8 + hh] = a2;
  }
}

// ---------------------------------------------------------------- GAT aggregate core
// one wave per dst node, single pass (no max subtraction: |e| << 1, exp safe)
template <int FOUT, int H, int C>
__device__ __forceinline__ void gat_agg_core(
    const float* __restrict__ h, const float* __restrict__ as_,
    const float* __restrict__ ad_, const float* __restrict__ b,
    const int* __restrict__ offs, const int* __restrict__ csr,
    int nd, int lane, float (&o)[FOUT]) {
  int beg = offs[nd], end = offs[nd + 1];
  float adv[H]; loadf<H>(ad_ + nd * H, adv);
  float den[H]; float num[FOUT];
#pragma unroll
  for (int i = 0; i < H; ++i) den[i] = 0.f;
#pragma unroll
  for (int i = 0; i < FOUT; ++i) num[i] = 0.f;
  for (int idx = beg + lane; idx < end; idx += 64) {
    int sv = csr[idx];
    float av[H]; loadf<H>(as_ + sv * H, av);
    float hv[FOUT]; loadf<FOUT>(h + sv * FOUT, hv);
#pragma unroll
    for (int hh = 0; hh < H; ++hh) {
      float e = av[hh] + adv[hh];
      e = (e >= 0.f) ? e : 0.2f * e;
      float ex = __expf(e);
      den[hh] += ex;
#pragma unroll
      for (int c = 0; c < C; ++c) num[hh * C + c] += ex * hv[hh * C + c];
    }
  }
#pragma unroll
  for (int hh = 0; hh < H; ++hh) den[hh] = wred_sum(den[hh]);
#pragma unroll
  for (int f = 0; f < FOUT; ++f) num[f] = wred_sum(num[f]);
#pragma unroll
  for (int f = 0; f < FOUT; ++f) o[f] = num[f] / (den[f / C] + 1e-16f) + b[f];
}

// agg layer1 (16->32,H8C4) + layer2 node transform (32->16, H4C4)
__global__ __launch_bounds__(256) void k_agg1n2(
    const float* __restrict__ h, const float* __restrict__ as_,
    const float* __restrict__ ad_, const float* __restrict__ b,
    const int* __restrict__ offs, const int* __restrict__ csr,
    const float* __restrict__ W2, const float* __restrict__ a2s,
    const float* __restrict__ a2d,
    float* __restrict__ h2, float* __restrict__ as2, float* __restrict__ ad2, int n) {
  int wave = threadIdx.x >> 6, lane = threadIdx.x & 63;
  int nd = blockIdx.x * 4 + wave;
  if (nd >= n) return;
  float o[32];
  gat_agg_core<32, 8, 4>(h, as_, ad_, b, offs, csr, nd, lane, o);
  float hv = 0.f;
  if (lane < 16) {
#pragma unroll
    for (int c = 0; c < 32; ++c) hv += o[c] * W2[c * 16 + lane];
    h2[nd * 16 + lane] = hv;
  }
  float vs = (lane < 16) ? a2s[lane] : 0.f;
  float vd = (lane < 16) ? a2d[lane] : 0.f;
  float ts = hv * vs, td = hv * vd;
  ts += __shfl_xor(ts, 1, 64); ts += __shfl_xor(ts, 2, 64);
  td += __shfl_xor(td, 1, 64); td += __shfl_xor(td, 2, 64);
  if (lane < 16 && (lane & 3) == 0) {
    as2[nd * 4 + (lane >> 2)] = ts;
    ad2[nd * 4 + (lane >> 2)] = td;
  }
}

// agg layer2 (32->16,H4C4) + layer3 node transform (16->8, H2C4)
__global__ __launch_bounds__(256) void k_agg2n3(
    const float* __restrict__ h, const float* __restrict__ as_,
    const float* __restrict__ ad_, const float* __restrict__ b,
    const int* __restrict__ offs, const int* __restrict__ csr,
    const float* __restrict__ W3, const float* __restrict__ a3s,
    const float* __restrict__ a3d,
    float* __restrict__ h3, float* __restrict__ as3, float* __restrict__ ad3, int n) {
  int wave = threadIdx.x >> 6, lane = threadIdx.x & 63;
  int nd = blockIdx.x * 4 + wave;
  if (nd >= n) return;
  float o[16];
  gat_agg_core<16, 4, 4>(h, as_, ad_, b, offs, csr, nd, lane, o);
  float hv = 0.f;
  if (lane < 8) {
#pragma unroll
    for (int c = 0; c < 16; ++c) hv += o[c] * W3[c * 8 + lane];
    h3[nd * 8 + lane] = hv;
  }
  float vs = (lane < 8) ? a3s[lane] : 0.f;
  float vd = (lane < 8) ? a3d[lane] : 0.f;
  float ts = hv * vs, td = hv * vd;
  ts += __shfl_xor(ts, 1, 64); ts += __shfl_xor(ts, 2, 64);
  td += __shfl_xor(td, 1, 64); td += __shfl_xor(td, 2, 64);
  if (lane < 8 && (lane & 3) == 0) {
    as3[nd * 2 + (lane >> 2)] = ts;
    ad3[nd * 2 + (lane >> 2)] = td;
  }
}

// agg layer3 (16->8,H2C4) -> x4
__global__ __launch_bounds__(256) void k_agg3(
    const float* __restrict__ h, const float* __restrict__ as_,
    const float* __restrict__ ad_, const float* __restrict__ b,
    const int* __restrict__ offs, const int* __restrict__ csr,
    float* __restrict__ x4, int n) {
  int wave = threadIdx.x >> 6, lane = threadIdx.x & 63;
  int nd = blockIdx.x * 4 + wave;
  if (nd >= n) return;
  float o[8];
  gat_agg_core<8, 2, 4>(h, as_, ad_, b, offs, csr, nd, lane, o);
  if (lane < 8) x4[nd * 8 + lane] = o[lane];
}

// ---------------------------------------------------------------- final scores
__global__ __launch_bounds__(256) void k_final(
    const float* __restrict__ x4, const unsigned int* __restrict__ bits,
    const float* __restrict__ w2, float* __restrict__ out, int n, int wpr) {
  int wave = threadIdx.x >> 6, lane = threadIdx.x & 63;
  int row = blockIdx.x * 4 + wave;
  if (row >= n) return;
  float sum[8];
#pragma unroll
  for (int c = 0; c < 8; ++c) sum[c] = 0.f;
  int cnt = 0;
  for (int w = lane; w < wpr; w += 64) {
    unsigned int word = bits[(size_t)row * wpr + w];
    cnt += __popc(word);
    while (word) {
      int bpos = __ffs(word) - 1;
      word &= word - 1;
      int j = w * 32 + bpos;
      float xv[8]; loadf<8>(x4 + j * 8, xv);
#pragma unroll
      for (int c = 0; c < 8; ++c) sum[c] += xv[c];
    }
  }
  cnt = (int)wred_sum((float)cnt);
#pragma unroll
  for (int c = 0; c < 8; ++c) sum[c] = wred_sum(sum[c]);
  if (lane == 0) {
    float inv = 1.f / (float)cnt;
    float xr[8]; loadf<8>(x4 + row * 8, xr);
    float local = 0.f, glob = 0.f;
#pragma unroll
    for (int c = 0; c < 8; ++c) {
      float r = sum[c] * inv;
      local += xr[c] * r;
      glob += r * w2[c];
    }
    out[row] = local + glob;
  }
}

// ---------------------------------------------------------------- launch
extern "C" void kernel_launch(void* const* d_in, const int* in_sizes, int n_in,
                              void* d_out, int out_size, void* d_ws, size_t ws_size,
                              hipStream_t stream) {
  const float* x1 = (const float*)d_in[0];
  const float* x2 = (const float*)d_in[1];
  const int* ei = (const int*)d_in[2];
  const float* qw = (const float*)d_in[4];
  const float* qb = (const float*)d_in[5];
  const float* kw = (const float*)d_in[6];
  const float* kb = (const float*)d_in[7];
  const float* vw = (const float*)d_in[8];
  const float* vb = (const float*)d_in[9];
  const float* W1 = (const float*)d_in[10];
  const float* a1s = (const float*)d_in[11];
  const float* a1d = (const float*)d_in[12];
  const float* b1 = (const float*)d_in[13];
  const float* W2 = (const float*)d_in[14];
  const float* a2s = (const float*)d_in[15];
  const float* a2d = (const float*)d_in[16];
  const float* b2 = (const float*)d_in[17];
  const float* W3 = (const float*)d_in[18];
  const float* a3s = (const float*)d_in[19];
  const float* a3d = (const float*)d_in[20];
  const float* b3 = (const float*)d_in[21];
  const float* w2 = (const float*)d_in[22];

  const int N = in_sizes[0] / 10;
  const int E = in_sizes[2] / 2;
  const int* ei0 = ei;
  const int* ei1 = ei + E;
  const int wpr = (N + 31) / 32;

  char* w = (char*)d_ws;
  auto alloc = [&](size_t bytes) {
    void* p = (void*)w;
    w += (bytes + 255) & ~(size_t)255;
    return p;
  };
  // keep indeg/cursor/bits adjacent: one memset clears all three
  int* indeg    = (int*)alloc((size_t)N * 4);
  int* cursor   = (int*)alloc((size_t)N * 4);
  unsigned int* bits = (unsigned int*)alloc((size_t)N * wpr * 4);
  float* s_buf  = (float*)alloc((size_t)N * 4);
  float* v_buf  = (float*)alloc((size_t)N * 16 * 4);
  int* offs     = (int*)alloc((size_t)(N + 1) * 4);
  int* csr_src  = (int*)alloc((size_t)(E + N) * 4);
  float* hb1    = (float*)alloc((size_t)N * 32 * 4);
  float* ab1s   = (float*)alloc((size_t)N * 8 * 4);
  float* ab1d   = (float*)alloc((size_t)N * 8 * 4);
  float* hb2    = (float*)alloc((size_t)N * 16 * 4);
  float* ab2s   = (float*)alloc((size_t)N * 4 * 4);
  float* ab2d   = (float*)alloc((size_t)N * 4 * 4);
  float* hb3    = (float*)alloc((size_t)N * 8 * 4);
  float* ab3s   = (float*)alloc((size_t)N * 2 * 4);
  float* ab3d   = (float*)alloc((size_t)N * 2 * 4);
  float* x4     = (float*)alloc((size_t)N * 8 * 4);

  hipMemsetAsync(indeg, 0, (size_t)N * 4 * 2 + (size_t)N * wpr * 4, stream);

  const int TB = 256;
  int nb_edges = (E + N + TB - 1) / TB;
  int nb_waves = (N + 3) / 4;

  k_fuse1_prep<<<nb_edges, TB, 0, stream>>>(x1, x2, qw, qb, kw, kb, vw, vb,
                                            s_buf, v_buf, ei0, ei1, indeg, bits, E, N, wpr);
  k_scan<<<1, 1024, 0, stream>>>(indeg, offs, N);
  k_scatter<<<nb_edges, TB, 0, stream>>>(ei0, ei1, offs, cursor, csr_src, E, N);
  k_fuse2n1<<<(N + TB - 1) / TB, TB, 0, stream>>>(s_buf, v_buf, W1, a1s, a1d,
                                                  hb1, ab1s, ab1d, N);
  k_agg1n2<<<nb_waves, TB, 0, stream>>>(hb1, ab1s, ab1d, b1, offs, csr_src,
                                        W2, a2s, a2d, hb2, ab2s, ab2d, N);
  k_agg2n3<<<nb_waves, TB, 0, stream>>>(hb2, ab2s, ab2d, b2, offs, csr_src,
                                        W3, a3s, a3d, hb3, ab3s, ab3d, N);
  k_agg3<<<nb_waves, TB, 0, stream>>>(hb3, ab3s, ab3d, b3, offs, csr_src, x4, N);
  k_final<<<nb_waves, TB, 0, stream>>>(x4, bits, w2, (float*)d_out, N, wpr);
}